// Round 5
// baseline (304.427 us; speedup 1.0000x reference)
//
#include <hip/hip_runtime.h>
#include <hip/hip_bf16.h>

// GCN: 3 layers of  h = h + relu( segment_sum( norm * (h@W^T+b)[row], col ) )
// norm[e] = dis[row]*dis[col]*(row!=col), dis[v] = deg_row(v)>0 ? rsqrt(deg) : 0
// N=50000, D=128, E=800000. Harness compares in bf16 space (threshold 0.108):
// hW / GEMM inputs carried in bf16, accumulation fp32.
//
// R16: agg gathers PREDICATED (group-uniform exec-mask) instead of
// index-clamped. Poisson(16) degrees under 16-slot rounds fetched
// E[16*ceil(d/16)] ~= 23 slots vs 15.7 needed = +46% redundant line
// requests; under the line-miss-throughput (MSHR) model that's the pace
// setter, not FLOPs or raw BW. Each slot's epack+row loads now sit in
// `if (ik < end)` (uniform per 16-lane group -> exec-mask only, no
// divergence); e/p default 0 so the unconditional FMA block is NaN-safe.
// R15 (kept): hist/scatter node-range halving (25KB LDS, 6 blocks/CU cap);
// partials layout unchanged. 295.5us best.
// R12 (kept): 16 edges/round, 4 independent epack+gather chains.
// R11 (kept): quad-row dwordx4 gathers; shfl_xor(16|32) cross-group reduce.
// Kept lessons: no cooperative fusion (R7); no NT hints; packed-u8 counters
// valid (max degree ~45); don't fuse GEMM into big-LDS kernels (R13); global
// atomics at <64K-address density are contention-bound (R14: 74us @ 9% BW).

#define D_DIM 128
#define SCAN_CHUNK 1024
#define CHUNKS 256         // edge chunks
#define GROUPS 8
#define GS (CHUNKS / GROUPS)   // 32 chunks per group
#define LDSW 12512         // packed words: 4 bins/word -> 50048 bins >= N
#define HALVES 2
#define HWRD (LDSW / HALVES)   // 6256 words per half (25KB LDS)
#define HBINS (HWRD * 4)       // 25024 bins per half

typedef __attribute__((ext_vector_type(8))) short bf16x8;
typedef __attribute__((ext_vector_type(4))) float f32x4;

static __device__ __forceinline__ short f2bf(float f) {
    union { __hip_bfloat16 b; short s; } u;
    u.b = __float2bfloat16(f);
    return u.s;
}
static __device__ __forceinline__ float bf_lo(unsigned p) { return __uint_as_float(p << 16); }
static __device__ __forceinline__ float bf_hi(unsigned p) { return __uint_as_float(p & 0xffff0000u); }

// ---------------- CSR build (no global atomics, packed u8) ------------------

// grid (CHUNKS, 5): y=0/1 col histogram half 0/1, y=2/3 row histogram half
// 0/1, y=4 W->bf16 convert. 25KB LDS -> 6 blocks/CU cap (was 3 at 50KB).
__global__ __launch_bounds__(256) void hist_kernel(const int* __restrict__ ei,
                                                   unsigned* __restrict__ partial_col,
                                                   unsigned* __restrict__ partial_row,
                                                   const float* __restrict__ W0,
                                                   const float* __restrict__ W1,
                                                   const float* __restrict__ W2,
                                                   unsigned short* __restrict__ Wb,
                                                   int E, int CHSZ) {
    int tid = threadIdx.x;
    if (blockIdx.y == 4) {                          // wcvt slice: 3*16384 elems
        int i = blockIdx.x * 256 + tid;
        if (i < 3 * D_DIM * D_DIM) {
            const float* W = (i < 16384) ? W0 : (i < 32768) ? W1 : W2;
            Wb[i] = (unsigned short)f2bf(W[i & 16383]);
        }
        return;
    }
    __shared__ unsigned hh[HWRD];
    int ch = blockIdx.x;
    int docol = (blockIdx.y < 2);
    int half = blockIdx.y & 1;
    int bin0 = half * HBINS;
    for (int i = tid; i < HWRD; i += 256) hh[i] = 0u;
    __syncthreads();
    int e0 = ch * CHSZ, e1 = min(e0 + CHSZ, E);
    for (int e = e0 + tid; e < e1; e += 256) {
        int row = ei[e];
        int col = ei[E + e];
        if (row == col) continue;                  // remove_self_loops
        int rb = (docol ? col : row) - bin0;
        if ((unsigned)rb < (unsigned)HBINS)
            atomicAdd(&hh[rb >> 2], 1u << ((rb & 3) * 8));
    }
    __syncthreads();
    unsigned* dst = (docol ? partial_col : partial_row) + (size_t)ch * LDSW + half * HWRD;
    for (int i = tid; i < HWRD; i += 256) dst[i] = hh[i];
}

// grid (ceil(NW/256), GROUPS, 2). z=0: in-place exclusive prefix of col counts
// over the group's GS chunks + group sum. z=1: row group sums only.
__global__ __launch_bounds__(256) void group_prefix_kernel(
    unsigned* __restrict__ partial_col, const unsigned* __restrict__ partial_row,
    unsigned* __restrict__ gsum_col, unsigned* __restrict__ gsum_row, int NW) {
    int w = blockIdx.x * 256 + threadIdx.x;
    if (w >= NW) return;
    int g = blockIdx.y;
    size_t base = (size_t)(g * GS) * LDSW + w;
    if (blockIdx.z == 0) {
        unsigned run = 0;
#pragma unroll 4
        for (int c = 0; c < GS; c++) {
            unsigned v = partial_col[base + (size_t)c * LDSW];
            partial_col[base + (size_t)c * LDSW] = run;
            run += v;
        }
        gsum_col[g * NW + w] = run;
    } else {
        unsigned run = 0;
#pragma unroll 4
        for (int c = 0; c < GS; c++) run += partial_row[base + (size_t)c * LDSW];
        gsum_row[g * NW + w] = run;
    }
}

// per packed word: sum the GROUPS group words -> col_cnt int4, dis float4,
// per-SCAN_CHUNK block sums, AND in-place exclusive prefix of gsum_col over
// groups (values already in registers -- replaces the gpref launch).
__global__ __launch_bounds__(256) void cnt_dis_kernel(
    unsigned* __restrict__ gsum_col, const unsigned* __restrict__ gsum_row,
    int* __restrict__ col_cnt, float* __restrict__ dis, int* __restrict__ bsum, int NW) {
    __shared__ int wsum[4];
    int w = blockIdx.x * 256 + threadIdx.x;
    int s = 0;
    if (w < NW) {
        unsigned wcv[GROUPS];
        unsigned clo = 0, chi = 0, rlo = 0, rhi = 0;
#pragma unroll
        for (int g = 0; g < GROUPS; g++) {
            unsigned wc = gsum_col[g * NW + w];
            unsigned wr = gsum_row[g * NW + w];
            wcv[g] = wc;
            clo += wc & 0x00FF00FFu; chi += (wc >> 8) & 0x00FF00FFu;
            rlo += wr & 0x00FF00FFu; rhi += (wr >> 8) & 0x00FF00FFu;
        }
        unsigned run = 0;
#pragma unroll
        for (int g = 0; g < GROUPS; g++) {         // exclusive prefix (packed u8)
            gsum_col[g * NW + w] = run;
            run += wcv[g];
        }
        int c0 = clo & 0xFFFF, c1 = chi & 0xFFFF, c2 = clo >> 16, c3 = chi >> 16;
        int r0 = rlo & 0xFFFF, r1 = rhi & 0xFFFF, r2 = rlo >> 16, r3 = rhi >> 16;
        ((int4*)col_cnt)[w] = make_int4(c0, c1, c2, c3);
        float4 dv;
        dv.x = (r0 > 0) ? rsqrtf((float)r0) : 0.0f;
        dv.y = (r1 > 0) ? rsqrtf((float)r1) : 0.0f;
        dv.z = (r2 > 0) ? rsqrtf((float)r2) : 0.0f;
        dv.w = (r3 > 0) ? rsqrtf((float)r3) : 0.0f;
        ((float4*)dis)[w] = dv;
        s = c0 + c1 + c2 + c3;
    }
#pragma unroll
    for (int d = 32; d > 0; d >>= 1) s += __shfl_down(s, d, 64);
    int lane = threadIdx.x & 63, wv = threadIdx.x >> 6;
    if (lane == 0) wsum[wv] = s;
    __syncthreads();
    if (threadIdx.x == 0) bsum[blockIdx.x] = wsum[0] + wsum[1] + wsum[2] + wsum[3];
}

// grid (G): local exclusive scan + inline cross-block base (wave 0 scans the
// G<=64 bsums redundantly per block).
__global__ __launch_bounds__(256) void scan_final_kernel(const int* __restrict__ cnt,
                                                         const int* __restrict__ bsum,
                                                         int* __restrict__ offs,
                                                         int n, int G) {
    __shared__ int wsum[4];
    __shared__ int sblock;
    int base = blockIdx.x * SCAN_CHUNK;
    int tid = threadIdx.x;
    const int PT = SCAN_CHUNK / 256;
    int v[PT];
    int s = 0;
#pragma unroll
    for (int i = 0; i < PT; i++) {
        int g = base + tid * PT + i;
        v[i] = (g < n) ? cnt[g] : 0;
        s += v[i];
    }
    int local_sum = s;
    int lane = tid & 63, w = tid >> 6;
#pragma unroll
    for (int d = 1; d < 64; d <<= 1) {
        int t = __shfl_up(s, d, 64);
        if (lane >= d) s += t;
    }
    if (lane == 63) wsum[w] = s;
    if (tid < 64) {
        int bv = (tid < G) ? bsum[tid] : 0;
        int bs = bv;
#pragma unroll
        for (int d = 1; d < 64; d <<= 1) {
            int t = __shfl_up(bs, d, 64);
            if (tid >= d) bs += t;
        }
        if (tid == blockIdx.x) sblock = bs - bv;            // exclusive base
        if (tid == 63 && blockIdx.x == G - 1) offs[n] = bs; // grand total
    }
    __syncthreads();
    int wbase = 0;
    for (int i = 0; i < w; i++) wbase += wsum[i];
    int run = sblock + wbase + (s - local_sum);
#pragma unroll
    for (int i = 0; i < PT; i++) {
        int g = base + tid * PT + i;
        if (g < n) offs[g] = run;
        run += v[i];
    }
}

// grid (CHUNKS, HALVES): LDS cursors (25KB, half the node range) seeded with
// chunk_prefix + group-exclusive base. slot = offs[col] + byte(old).
// epack entry: row:u16 | norm:bf16. Edges outside the half are skipped.
__global__ __launch_bounds__(256) void scatter_kernel(const int* __restrict__ ei,
                                                      const float* __restrict__ dis,
                                                      const int* __restrict__ offs,
                                                      const unsigned* __restrict__ chpref,
                                                      const unsigned* __restrict__ gpref,
                                                      unsigned* __restrict__ epack,
                                                      int E, int CHSZ, int NW) {
    __shared__ unsigned cur[HWRD];
    int tid = threadIdx.x;
    int ch = blockIdx.x;
    int half = blockIdx.y;
    int wbase = half * HWRD;                       // word offset of this half
    int bin0 = half * HBINS;
    const unsigned* pf = chpref + (size_t)ch * LDSW + wbase;
    const unsigned* gb = gpref + (size_t)(ch / GS) * NW;
    for (int i = tid; i < HWRD; i += 256) {
        unsigned seed = pf[i];
        int w = wbase + i;
        if (w < NW) seed += gb[w];
        cur[i] = seed;
    }
    __syncthreads();
    int e0 = ch * CHSZ, e1 = min(e0 + CHSZ, E);
    for (int e = e0 + tid; e < e1; e += 256) {
        int row = ei[e];
        int col = ei[E + e];
        if (row == col) continue;
        int rb = col - bin0;
        if ((unsigned)rb >= (unsigned)HBINS) continue;   // other half
        float wgt = dis[row] * dis[col];
        int wd = rb >> 2, sh = (rb & 3) * 8;
        unsigned old = atomicAdd(&cur[wd], 1u << sh);
        int slot = offs[col] + (int)((old >> sh) & 0xFFu);
        epack[slot] = (unsigned)row | ((unsigned)(unsigned short)f2bf(wgt) << 16);
    }
}

// ---------------- per-layer kernels ----------------------------------------

// hWb[r][j] = bf16( b[j] + sum_k h[r][k] * W[j][k] )  via 16x16x32 bf16 MFMA.
// Wave: 16 rows x 128 cols. C/D layout: col=lane&15, row=(lane>>4)*4+reg.
// Epilogue stages the bf16 tile in LDS then stores 4x contiguous 1KB/wave.
__global__ __launch_bounds__(256) void linear_mfma_kernel(
    const float* __restrict__ A, const unsigned short* __restrict__ Wb,
    const float* __restrict__ bias, unsigned short* __restrict__ hWb, int nrows) {
    __shared__ unsigned short stage[4][16 * 136];
    int wave = threadIdx.x >> 6;
    int lane = threadIdx.x & 63;
    int r0 = blockIdx.x * 64 + wave * 16;
    int m = lane & 15, q = lane >> 4;
    int rload = min(r0 + m, nrows - 1);
    const float4* h4 = (const float4*)A;

    f32x4 acc[8];
#pragma unroll
    for (int jt = 0; jt < 8; jt++) acc[jt] = (f32x4){0.f, 0.f, 0.f, 0.f};

#pragma unroll
    for (int k0 = 0; k0 < 128; k0 += 32) {
        int c0 = k0 + q * 8;
        float4 x0 = h4[rload * 32 + (c0 >> 2)];
        float4 x1 = h4[rload * 32 + (c0 >> 2) + 1];
        bf16x8 a;
        a[0] = f2bf(x0.x); a[1] = f2bf(x0.y); a[2] = f2bf(x0.z); a[3] = f2bf(x0.w);
        a[4] = f2bf(x1.x); a[5] = f2bf(x1.y); a[6] = f2bf(x1.z); a[7] = f2bf(x1.w);
#pragma unroll
        for (int jt = 0; jt < 8; jt++) {
            bf16x8 b = *(const bf16x8*)(Wb + (jt * 16 + m) * D_DIM + c0);
            acc[jt] = __builtin_amdgcn_mfma_f32_16x16x32_bf16(a, b, acc[jt], 0, 0, 0);
        }
    }

#pragma unroll
    for (int jt = 0; jt < 8; jt++) {
        float bv = bias[jt * 16 + m];
#pragma unroll
        for (int reg = 0; reg < 4; reg++)
            stage[wave][(q * 4 + reg) * 136 + jt * 16 + m] =
                (unsigned short)f2bf(acc[jt][reg] + bv);
    }
#pragma unroll
    for (int t = 0; t < 4; t++) {
        int rl = t * 4 + (lane >> 4);
        int gr = r0 + rl;
        if (gr < nrows) {
            uint4 v = *(const uint4*)&stage[wave][rl * 136 + (lane & 15) * 8];
            *(uint4*)&hWb[(size_t)gr * D_DIM + (lane & 15) * 8] = v;
        }
    }
}

// one wave per destination node; quad-row gathers: lane (g=lane>>4, s=lane&15)
// loads 16B (dims 8s..8s+7) of an edge row per dwordx4. 16 edges/round --
// group g takes slots i+g, i+4+g, i+8+g, i+12+g. R16: slot loads are
// PREDICATED (group-uniform if, exec-mask only) instead of index-clamped:
// skips the +46% redundant tail-line requests entirely (e/p default 0 keeps
// the unconditional FMA block NaN-safe). fp32 acc; shfl_xor(16|32)
// cross-group reduce; group-0 float4 epilogue h_out = h_prev + relu(acc).
__global__ __launch_bounds__(256) void agg_kernel(const int* __restrict__ offs,
                                                  const unsigned* __restrict__ epack,
                                                  const uint4* __restrict__ hW4,
                                                  const float* __restrict__ hprev,
                                                  float* __restrict__ hout, int n_nodes) {
    int node = (int)((blockIdx.x * blockDim.x + threadIdx.x) >> 6);
    int lane = threadIdx.x & 63;
    if (node >= n_nodes) return;
    int g = lane >> 4, s = lane & 15;

    int beg = offs[node];
    int end = offs[node + 1];

    float acc[8];
#pragma unroll
    for (int k = 0; k < 8; k++) acc[k] = 0.f;

    for (int i = beg; i < end; i += 16) {
        int i0 = i + g, i1 = i0 + 4, i2 = i0 + 8, i3 = i0 + 12;
        unsigned e0 = 0u, e1 = 0u, e2 = 0u, e3 = 0u;
        uint4 p0 = make_uint4(0u, 0u, 0u, 0u);
        uint4 p1 = make_uint4(0u, 0u, 0u, 0u);
        uint4 p2 = make_uint4(0u, 0u, 0u, 0u);
        uint4 p3 = make_uint4(0u, 0u, 0u, 0u);
        if (i0 < end) { e0 = epack[i0]; p0 = hW4[(e0 & 0xffffu) * 16 + s]; }
        if (i1 < end) { e1 = epack[i1]; p1 = hW4[(e1 & 0xffffu) * 16 + s]; }
        if (i2 < end) { e2 = epack[i2]; p2 = hW4[(e2 & 0xffffu) * 16 + s]; }
        if (i3 < end) { e3 = epack[i3]; p3 = hW4[(e3 & 0xffffu) * 16 + s]; }
        float w0 = bf_hi(e0), w1 = bf_hi(e1), w2 = bf_hi(e2), w3 = bf_hi(e3);
        acc[0] = fmaf(w0, bf_lo(p0.x), acc[0]); acc[1] = fmaf(w0, bf_hi(p0.x), acc[1]);
        acc[2] = fmaf(w0, bf_lo(p0.y), acc[2]); acc[3] = fmaf(w0, bf_hi(p0.y), acc[3]);
        acc[4] = fmaf(w0, bf_lo(p0.z), acc[4]); acc[5] = fmaf(w0, bf_hi(p0.z), acc[5]);
        acc[6] = fmaf(w0, bf_lo(p0.w), acc[6]); acc[7] = fmaf(w0, bf_hi(p0.w), acc[7]);
        acc[0] = fmaf(w1, bf_lo(p1.x), acc[0]); acc[1] = fmaf(w1, bf_hi(p1.x), acc[1]);
        acc[2] = fmaf(w1, bf_lo(p1.y), acc[2]); acc[3] = fmaf(w1, bf_hi(p1.y), acc[3]);
        acc[4] = fmaf(w1, bf_lo(p1.z), acc[4]); acc[5] = fmaf(w1, bf_hi(p1.z), acc[5]);
        acc[6] = fmaf(w1, bf_lo(p1.w), acc[6]); acc[7] = fmaf(w1, bf_hi(p1.w), acc[7]);
        acc[0] = fmaf(w2, bf_lo(p2.x), acc[0]); acc[1] = fmaf(w2, bf_hi(p2.x), acc[1]);
        acc[2] = fmaf(w2, bf_lo(p2.y), acc[2]); acc[3] = fmaf(w2, bf_hi(p2.y), acc[3]);
        acc[4] = fmaf(w2, bf_lo(p2.z), acc[4]); acc[5] = fmaf(w2, bf_hi(p2.z), acc[5]);
        acc[6] = fmaf(w2, bf_lo(p2.w), acc[6]); acc[7] = fmaf(w2, bf_hi(p2.w), acc[7]);
        acc[0] = fmaf(w3, bf_lo(p3.x), acc[0]); acc[1] = fmaf(w3, bf_hi(p3.x), acc[1]);
        acc[2] = fmaf(w3, bf_lo(p3.y), acc[2]); acc[3] = fmaf(w3, bf_hi(p3.y), acc[3]);
        acc[4] = fmaf(w3, bf_lo(p3.z), acc[4]); acc[5] = fmaf(w3, bf_hi(p3.z), acc[5]);
        acc[6] = fmaf(w3, bf_lo(p3.w), acc[6]); acc[7] = fmaf(w3, bf_hi(p3.w), acc[7]);
    }

#pragma unroll
    for (int k = 0; k < 8; k++) {                   // sum the 4 groups
        acc[k] += __shfl_xor(acc[k], 16, 64);
        acc[k] += __shfl_xor(acc[k], 32, 64);
    }

    if (g == 0) {                                   // lanes 0..15 own dims 8s..8s+7
        const float4* hp4 = (const float4*)hprev;
        float4* ho4 = (float4*)hout;
        int idx = node * 32 + s * 2;
        float4 h0 = hp4[idx], h1 = hp4[idx + 1];
        float4 o0, o1;
        o0.x = h0.x + fmaxf(acc[0], 0.f); o0.y = h0.y + fmaxf(acc[1], 0.f);
        o0.z = h0.z + fmaxf(acc[2], 0.f); o0.w = h0.w + fmaxf(acc[3], 0.f);
        o1.x = h1.x + fmaxf(acc[4], 0.f); o1.y = h1.y + fmaxf(acc[5], 0.f);
        o1.z = h1.z + fmaxf(acc[6], 0.f); o1.w = h1.w + fmaxf(acc[7], 0.f);
        ho4[idx] = o0;
        ho4[idx + 1] = o1;
    }
}

// ---------------- launch ----------------------------------------------------

static inline size_t align_up(size_t x, size_t a) { return (x + a - 1) & ~(a - 1); }

extern "C" void kernel_launch(void* const* d_in, const int* in_sizes, int n_in,
                              void* d_out, int out_size, void* d_ws, size_t ws_size,
                              hipStream_t stream) {
    const float* x = (const float*)d_in[0];
    const int* ei = (const int*)d_in[1];
    const float* Wl[3] = {(const float*)d_in[2], (const float*)d_in[4], (const float*)d_in[6]};
    const float* bl[3] = {(const float*)d_in[3], (const float*)d_in[5], (const float*)d_in[7]};

    const int N = in_sizes[0] / D_DIM;                 // 50000 (requires N <= 4*LDSW, N < 65536)
    const int E = in_sizes[1] / 2;                     // 800000
    const int NW = N / 4;                              // 12500 packed words
    const int G = (N + SCAN_CHUNK - 1) / SCAN_CHUNK;   // 49 (must be <= 64)
    const int NWB = (NW + 255) / 256;                  // 49 word-blocks
    const int CHSZ = (E + CHUNKS - 1) / CHUNKS;        // 3125

    char* p = (char*)d_ws;
    int* col_cnt = (int*)p;            p += align_up((size_t)N * 4, 256);
    int* offs    = (int*)p;            p += align_up((size_t)(N + 1) * 4, 256);
    float* dis   = (float*)p;          p += align_up((size_t)N * 4, 256);
    int* bsum    = (int*)p;            p += align_up((size_t)64 * 4, 256);
    unsigned* partial_col = (unsigned*)p;  p += align_up((size_t)CHUNKS * LDSW * 4, 256);
    unsigned* partial_row = (unsigned*)p;  p += align_up((size_t)CHUNKS * LDSW * 4, 256);
    unsigned* gsum_col = (unsigned*)p; p += align_up((size_t)GROUPS * NW * 4, 256);
    unsigned* gsum_row = (unsigned*)p; p += align_up((size_t)GROUPS * NW * 4, 256);
    unsigned short* Wb = (unsigned short*)p;  p += align_up((size_t)3 * D_DIM * D_DIM * 2, 256);
    unsigned* epack = (unsigned*)p;    p += align_up((size_t)E * 4, 256);
    unsigned short* hWb = (unsigned short*)p;  p += align_up((size_t)N * D_DIM * 2, 256);
    (void)ws_size;

    hist_kernel<<<dim3(CHUNKS, 5), 256, 0, stream>>>(ei, partial_col, partial_row,
                                                     Wl[0], Wl[1], Wl[2], Wb, E, CHSZ);
    group_prefix_kernel<<<dim3(NWB, GROUPS, 2), 256, 0, stream>>>(partial_col, partial_row,
                                                                  gsum_col, gsum_row, NW);
    cnt_dis_kernel<<<NWB, 256, 0, stream>>>(gsum_col, gsum_row, col_cnt, dis, bsum, NW);
    scan_final_kernel<<<G, 256, 0, stream>>>(col_cnt, bsum, offs, N, G);
    scatter_kernel<<<dim3(CHUNKS, HALVES), 256, 0, stream>>>(ei, dis, offs, partial_col,
                                                             gsum_col, epack, E, CHSZ, NW);

    const float* hprev = x;
    float* h = (float*)d_out;
    int gemm_blocks = (N + 63) / 64;
    int agg_blocks = (N + 3) / 4;
    for (int l = 0; l < 3; l++) {
        linear_mfma_kernel<<<gemm_blocks, 256, 0, stream>>>(hprev, Wb + l * 16384, bl[l], hWb, N);
        agg_kernel<<<agg_blocks, 256, 0, stream>>>(offs, epack, (const uint4*)hWb, hprev, h, N);
        hprev = h;
    }
}

// Round 6
// 294.545 us; speedup vs baseline: 1.0335x; 1.0335x over previous
//
#include <hip/hip_runtime.h>
#include <hip/hip_bf16.h>

// GCN: 3 layers of  h = h + relu( segment_sum( norm * (h@W^T+b)[row], col ) )
// norm[e] = dis[row]*dis[col]*(row!=col), dis[v] = deg_row(v)>0 ? rsqrt(deg) : 0
// N=50000, D=128, E=800000. Harness compares in bf16 space (threshold 0.108):
// hW / GEMM inputs carried in bf16, accumulation fp32.
//
// R17: (a) agg reverted to R15 index-CLAMP form -- R16 predication regressed
// +9us: same-line tail dupes are free (L1/L2-resident), per-load exec-mask
// branches broke the 4-chain back-to-back issue. (b) CHUNKS 256->128: halves
// all partials traffic (~300MB -> ~150MB ~= -24us of HBM across hist/
// group_prefix/scatter); total edge-scan work is CHUNKS-independent. hist
// grid.x widened to 192 for the wcvt slice (ch guard added). (c) scatter
// moves to QUARTER-split (12.5KB LDS, 4 y-slices) to keep 512 blocks / 2 per
// CU at CHUNKS=128 (half-split would be 256 blocks = 1/CU latency cliff);
// costs one extra edge pass (+12.8MB ~= +2us).
// R15 (kept): hist node-range halving (25KB LDS, 6 blocks/CU cap).
// R12 (kept): agg 16 edges/round, 4 independent epack+gather chains, clamp
// tails. agg is gather-throughput-bound at its L2/L3 service floor.
// R11 (kept): quad-row dwordx4 gathers; shfl_xor(16|32) cross-group reduce.
// Kept lessons: no cooperative fusion (R7); no NT hints; packed-u8 counters
// valid (max degree ~45); don't fuse GEMM into big-LDS kernels (R13); global
// atomics at <64K-address density are contention-bound (R14: 74us @ 9% BW);
// predicated gathers lose to clamped gathers (R16).

#define D_DIM 128
#define SCAN_CHUNK 1024
#define CHUNKS 128         // edge chunks
#define GROUPS 8
#define GS (CHUNKS / GROUPS)   // 16 chunks per group
#define LDSW 12512         // packed words: 4 bins/word -> 50048 bins >= N
#define HALVES 2
#define HWRD (LDSW / HALVES)   // 6256 words per half (25KB LDS) -- hist
#define HBINS (HWRD * 4)       // 25024 bins per half
#define QUARTERS 4
#define QWRD (LDSW / QUARTERS) // 3128 words per quarter (12.5KB LDS) -- scatter
#define QBINS (QWRD * 4)       // 12512 bins per quarter

typedef __attribute__((ext_vector_type(8))) short bf16x8;
typedef __attribute__((ext_vector_type(4))) float f32x4;

static __device__ __forceinline__ short f2bf(float f) {
    union { __hip_bfloat16 b; short s; } u;
    u.b = __float2bfloat16(f);
    return u.s;
}
static __device__ __forceinline__ float bf_lo(unsigned p) { return __uint_as_float(p << 16); }
static __device__ __forceinline__ float bf_hi(unsigned p) { return __uint_as_float(p & 0xffff0000u); }

// ---------------- CSR build (no global atomics, packed u8) ------------------

// grid (192, 5): y=0/1 col histogram half 0/1, y=2/3 row histogram half 0/1,
// y=4 W->bf16 convert. Edge slices use blocks [0,CHUNKS); wcvt uses all 192.
__global__ __launch_bounds__(256) void hist_kernel(const int* __restrict__ ei,
                                                   unsigned* __restrict__ partial_col,
                                                   unsigned* __restrict__ partial_row,
                                                   const float* __restrict__ W0,
                                                   const float* __restrict__ W1,
                                                   const float* __restrict__ W2,
                                                   unsigned short* __restrict__ Wb,
                                                   int E, int CHSZ) {
    int tid = threadIdx.x;
    if (blockIdx.y == 4) {                          // wcvt slice: 3*16384 elems
        int i = blockIdx.x * 256 + tid;
        if (i < 3 * D_DIM * D_DIM) {
            const float* W = (i < 16384) ? W0 : (i < 32768) ? W1 : W2;
            Wb[i] = (unsigned short)f2bf(W[i & 16383]);
        }
        return;
    }
    int ch = blockIdx.x;
    if (ch >= CHUNKS) return;                       // grid.x widened for wcvt
    __shared__ unsigned hh[HWRD];
    int docol = (blockIdx.y < 2);
    int half = blockIdx.y & 1;
    int bin0 = half * HBINS;
    for (int i = tid; i < HWRD; i += 256) hh[i] = 0u;
    __syncthreads();
    int e0 = ch * CHSZ, e1 = min(e0 + CHSZ, E);
    for (int e = e0 + tid; e < e1; e += 256) {
        int row = ei[e];
        int col = ei[E + e];
        if (row == col) continue;                  // remove_self_loops
        int rb = (docol ? col : row) - bin0;
        if ((unsigned)rb < (unsigned)HBINS)
            atomicAdd(&hh[rb >> 2], 1u << ((rb & 3) * 8));
    }
    __syncthreads();
    unsigned* dst = (docol ? partial_col : partial_row) + (size_t)ch * LDSW + half * HWRD;
    for (int i = tid; i < HWRD; i += 256) dst[i] = hh[i];
}

// grid (ceil(NW/256), GROUPS, 2). z=0: in-place exclusive prefix of col counts
// over the group's GS chunks + group sum. z=1: row group sums only.
__global__ __launch_bounds__(256) void group_prefix_kernel(
    unsigned* __restrict__ partial_col, const unsigned* __restrict__ partial_row,
    unsigned* __restrict__ gsum_col, unsigned* __restrict__ gsum_row, int NW) {
    int w = blockIdx.x * 256 + threadIdx.x;
    if (w >= NW) return;
    int g = blockIdx.y;
    size_t base = (size_t)(g * GS) * LDSW + w;
    if (blockIdx.z == 0) {
        unsigned run = 0;
#pragma unroll 4
        for (int c = 0; c < GS; c++) {
            unsigned v = partial_col[base + (size_t)c * LDSW];
            partial_col[base + (size_t)c * LDSW] = run;
            run += v;
        }
        gsum_col[g * NW + w] = run;
    } else {
        unsigned run = 0;
#pragma unroll 4
        for (int c = 0; c < GS; c++) run += partial_row[base + (size_t)c * LDSW];
        gsum_row[g * NW + w] = run;
    }
}

// per packed word: sum the GROUPS group words -> col_cnt int4, dis float4,
// per-SCAN_CHUNK block sums, AND in-place exclusive prefix of gsum_col over
// groups (values already in registers -- replaces the gpref launch).
__global__ __launch_bounds__(256) void cnt_dis_kernel(
    unsigned* __restrict__ gsum_col, const unsigned* __restrict__ gsum_row,
    int* __restrict__ col_cnt, float* __restrict__ dis, int* __restrict__ bsum, int NW) {
    __shared__ int wsum[4];
    int w = blockIdx.x * 256 + threadIdx.x;
    int s = 0;
    if (w < NW) {
        unsigned wcv[GROUPS];
        unsigned clo = 0, chi = 0, rlo = 0, rhi = 0;
#pragma unroll
        for (int g = 0; g < GROUPS; g++) {
            unsigned wc = gsum_col[g * NW + w];
            unsigned wr = gsum_row[g * NW + w];
            wcv[g] = wc;
            clo += wc & 0x00FF00FFu; chi += (wc >> 8) & 0x00FF00FFu;
            rlo += wr & 0x00FF00FFu; rhi += (wr >> 8) & 0x00FF00FFu;
        }
        unsigned run = 0;
#pragma unroll
        for (int g = 0; g < GROUPS; g++) {         // exclusive prefix (packed u8)
            gsum_col[g * NW + w] = run;
            run += wcv[g];
        }
        int c0 = clo & 0xFFFF, c1 = chi & 0xFFFF, c2 = clo >> 16, c3 = chi >> 16;
        int r0 = rlo & 0xFFFF, r1 = rhi & 0xFFFF, r2 = rlo >> 16, r3 = rhi >> 16;
        ((int4*)col_cnt)[w] = make_int4(c0, c1, c2, c3);
        float4 dv;
        dv.x = (r0 > 0) ? rsqrtf((float)r0) : 0.0f;
        dv.y = (r1 > 0) ? rsqrtf((float)r1) : 0.0f;
        dv.z = (r2 > 0) ? rsqrtf((float)r2) : 0.0f;
        dv.w = (r3 > 0) ? rsqrtf((float)r3) : 0.0f;
        ((float4*)dis)[w] = dv;
        s = c0 + c1 + c2 + c3;
    }
#pragma unroll
    for (int d = 32; d > 0; d >>= 1) s += __shfl_down(s, d, 64);
    int lane = threadIdx.x & 63, wv = threadIdx.x >> 6;
    if (lane == 0) wsum[wv] = s;
    __syncthreads();
    if (threadIdx.x == 0) bsum[blockIdx.x] = wsum[0] + wsum[1] + wsum[2] + wsum[3];
}

// grid (G): local exclusive scan + inline cross-block base (wave 0 scans the
// G<=64 bsums redundantly per block).
__global__ __launch_bounds__(256) void scan_final_kernel(const int* __restrict__ cnt,
                                                         const int* __restrict__ bsum,
                                                         int* __restrict__ offs,
                                                         int n, int G) {
    __shared__ int wsum[4];
    __shared__ int sblock;
    int base = blockIdx.x * SCAN_CHUNK;
    int tid = threadIdx.x;
    const int PT = SCAN_CHUNK / 256;
    int v[PT];
    int s = 0;
#pragma unroll
    for (int i = 0; i < PT; i++) {
        int g = base + tid * PT + i;
        v[i] = (g < n) ? cnt[g] : 0;
        s += v[i];
    }
    int local_sum = s;
    int lane = tid & 63, w = tid >> 6;
#pragma unroll
    for (int d = 1; d < 64; d <<= 1) {
        int t = __shfl_up(s, d, 64);
        if (lane >= d) s += t;
    }
    if (lane == 63) wsum[w] = s;
    if (tid < 64) {
        int bv = (tid < G) ? bsum[tid] : 0;
        int bs = bv;
#pragma unroll
        for (int d = 1; d < 64; d <<= 1) {
            int t = __shfl_up(bs, d, 64);
            if (tid >= d) bs += t;
        }
        if (tid == blockIdx.x) sblock = bs - bv;            // exclusive base
        if (tid == 63 && blockIdx.x == G - 1) offs[n] = bs; // grand total
    }
    __syncthreads();
    int wbase = 0;
    for (int i = 0; i < w; i++) wbase += wsum[i];
    int run = sblock + wbase + (s - local_sum);
#pragma unroll
    for (int i = 0; i < PT; i++) {
        int g = base + tid * PT + i;
        if (g < n) offs[g] = run;
        run += v[i];
    }
}

// grid (CHUNKS, QUARTERS): LDS cursors (12.5KB, quarter node range) seeded
// with chunk_prefix + group-exclusive base. slot = offs[col] + byte(old).
// epack entry: row:u16 | norm:bf16. Edges outside the quarter are skipped.
__global__ __launch_bounds__(256) void scatter_kernel(const int* __restrict__ ei,
                                                      const float* __restrict__ dis,
                                                      const int* __restrict__ offs,
                                                      const unsigned* __restrict__ chpref,
                                                      const unsigned* __restrict__ gpref,
                                                      unsigned* __restrict__ epack,
                                                      int E, int CHSZ, int NW) {
    __shared__ unsigned cur[QWRD];
    int tid = threadIdx.x;
    int ch = blockIdx.x;
    int q = blockIdx.y;
    int wbase = q * QWRD;                          // word offset of this quarter
    int bin0 = q * QBINS;
    const unsigned* pf = chpref + (size_t)ch * LDSW + wbase;
    const unsigned* gb = gpref + (size_t)(ch / GS) * NW;
    for (int i = tid; i < QWRD; i += 256) {
        unsigned seed = pf[i];
        int w = wbase + i;
        if (w < NW) seed += gb[w];
        cur[i] = seed;
    }
    __syncthreads();
    int e0 = ch * CHSZ, e1 = min(e0 + CHSZ, E);
    for (int e = e0 + tid; e < e1; e += 256) {
        int row = ei[e];
        int col = ei[E + e];
        if (row == col) continue;
        int rb = col - bin0;
        if ((unsigned)rb >= (unsigned)QBINS) continue;   // other quarter
        float wgt = dis[row] * dis[col];
        int wd = rb >> 2, sh = (rb & 3) * 8;
        unsigned old = atomicAdd(&cur[wd], 1u << sh);
        int slot = offs[col] + (int)((old >> sh) & 0xFFu);
        epack[slot] = (unsigned)row | ((unsigned)(unsigned short)f2bf(wgt) << 16);
    }
}

// ---------------- per-layer kernels ----------------------------------------

// hWb[r][j] = bf16( b[j] + sum_k h[r][k] * W[j][k] )  via 16x16x32 bf16 MFMA.
// Wave: 16 rows x 128 cols. C/D layout: col=lane&15, row=(lane>>4)*4+reg.
// Epilogue stages the bf16 tile in LDS then stores 4x contiguous 1KB/wave.
__global__ __launch_bounds__(256) void linear_mfma_kernel(
    const float* __restrict__ A, const unsigned short* __restrict__ Wb,
    const float* __restrict__ bias, unsigned short* __restrict__ hWb, int nrows) {
    __shared__ unsigned short stage[4][16 * 136];
    int wave = threadIdx.x >> 6;
    int lane = threadIdx.x & 63;
    int r0 = blockIdx.x * 64 + wave * 16;
    int m = lane & 15, q = lane >> 4;
    int rload = min(r0 + m, nrows - 1);
    const float4* h4 = (const float4*)A;

    f32x4 acc[8];
#pragma unroll
    for (int jt = 0; jt < 8; jt++) acc[jt] = (f32x4){0.f, 0.f, 0.f, 0.f};

#pragma unroll
    for (int k0 = 0; k0 < 128; k0 += 32) {
        int c0 = k0 + q * 8;
        float4 x0 = h4[rload * 32 + (c0 >> 2)];
        float4 x1 = h4[rload * 32 + (c0 >> 2) + 1];
        bf16x8 a;
        a[0] = f2bf(x0.x); a[1] = f2bf(x0.y); a[2] = f2bf(x0.z); a[3] = f2bf(x0.w);
        a[4] = f2bf(x1.x); a[5] = f2bf(x1.y); a[6] = f2bf(x1.z); a[7] = f2bf(x1.w);
#pragma unroll
        for (int jt = 0; jt < 8; jt++) {
            bf16x8 b = *(const bf16x8*)(Wb + (jt * 16 + m) * D_DIM + c0);
            acc[jt] = __builtin_amdgcn_mfma_f32_16x16x32_bf16(a, b, acc[jt], 0, 0, 0);
        }
    }

#pragma unroll
    for (int jt = 0; jt < 8; jt++) {
        float bv = bias[jt * 16 + m];
#pragma unroll
        for (int reg = 0; reg < 4; reg++)
            stage[wave][(q * 4 + reg) * 136 + jt * 16 + m] =
                (unsigned short)f2bf(acc[jt][reg] + bv);
    }
#pragma unroll
    for (int t = 0; t < 4; t++) {
        int rl = t * 4 + (lane >> 4);
        int gr = r0 + rl;
        if (gr < nrows) {
            uint4 v = *(const uint4*)&stage[wave][rl * 136 + (lane & 15) * 8];
            *(uint4*)&hWb[(size_t)gr * D_DIM + (lane & 15) * 8] = v;
        }
    }
}

// one wave per destination node; quad-row gathers: lane (g=lane>>4, s=lane&15)
// loads 16B (dims 8s..8s+7) of an edge row per dwordx4. 16 edges/round --
// group g takes slots i+g, i+4+g, i+8+g, i+12+g; 4 epack loads + 4 gathers
// issued as independent chains per round; ragged ends via index clamp +
// weight zeroing (R16: predication regressed; clamp dupes are free). fp32
// acc; shfl_xor(16|32) cross-group reduce; group-0 float4 epilogue
// h_out = h_prev + relu(acc).
__global__ __launch_bounds__(256) void agg_kernel(const int* __restrict__ offs,
                                                  const unsigned* __restrict__ epack,
                                                  const uint4* __restrict__ hW4,
                                                  const float* __restrict__ hprev,
                                                  float* __restrict__ hout, int n_nodes) {
    int node = (int)((blockIdx.x * blockDim.x + threadIdx.x) >> 6);
    int lane = threadIdx.x & 63;
    if (node >= n_nodes) return;
    int g = lane >> 4, s = lane & 15;

    int beg = offs[node];
    int end = offs[node + 1];

    float acc[8];
#pragma unroll
    for (int k = 0; k < 8; k++) acc[k] = 0.f;

    for (int i = beg; i < end; i += 16) {
        int last = end - 1;
        int i0 = i + g, i1 = i0 + 4, i2 = i0 + 8, i3 = i0 + 12;
        unsigned e0 = epack[min(i0, last)];
        unsigned e1 = epack[min(i1, last)];
        unsigned e2 = epack[min(i2, last)];
        unsigned e3 = epack[min(i3, last)];
        uint4 p0 = hW4[(e0 & 0xffffu) * 16 + s];
        uint4 p1 = hW4[(e1 & 0xffffu) * 16 + s];
        uint4 p2 = hW4[(e2 & 0xffffu) * 16 + s];
        uint4 p3 = hW4[(e3 & 0xffffu) * 16 + s];
        float w0 = (i0 < end) ? bf_hi(e0) : 0.f;
        float w1 = (i1 < end) ? bf_hi(e1) : 0.f;
        float w2 = (i2 < end) ? bf_hi(e2) : 0.f;
        float w3 = (i3 < end) ? bf_hi(e3) : 0.f;
        acc[0] = fmaf(w0, bf_lo(p0.x), acc[0]); acc[1] = fmaf(w0, bf_hi(p0.x), acc[1]);
        acc[2] = fmaf(w0, bf_lo(p0.y), acc[2]); acc[3] = fmaf(w0, bf_hi(p0.y), acc[3]);
        acc[4] = fmaf(w0, bf_lo(p0.z), acc[4]); acc[5] = fmaf(w0, bf_hi(p0.z), acc[5]);
        acc[6] = fmaf(w0, bf_lo(p0.w), acc[6]); acc[7] = fmaf(w0, bf_hi(p0.w), acc[7]);
        acc[0] = fmaf(w1, bf_lo(p1.x), acc[0]); acc[1] = fmaf(w1, bf_hi(p1.x), acc[1]);
        acc[2] = fmaf(w1, bf_lo(p1.y), acc[2]); acc[3] = fmaf(w1, bf_hi(p1.y), acc[3]);
        acc[4] = fmaf(w1, bf_lo(p1.z), acc[4]); acc[5] = fmaf(w1, bf_hi(p1.z), acc[5]);
        acc[6] = fmaf(w1, bf_lo(p1.w), acc[6]); acc[7] = fmaf(w1, bf_hi(p1.w), acc[7]);
        acc[0] = fmaf(w2, bf_lo(p2.x), acc[0]); acc[1] = fmaf(w2, bf_hi(p2.x), acc[1]);
        acc[2] = fmaf(w2, bf_lo(p2.y), acc[2]); acc[3] = fmaf(w2, bf_hi(p2.y), acc[3]);
        acc[4] = fmaf(w2, bf_lo(p2.z), acc[4]); acc[5] = fmaf(w2, bf_hi(p2.z), acc[5]);
        acc[6] = fmaf(w2, bf_lo(p2.w), acc[6]); acc[7] = fmaf(w2, bf_hi(p2.w), acc[7]);
        acc[0] = fmaf(w3, bf_lo(p3.x), acc[0]); acc[1] = fmaf(w3, bf_hi(p3.x), acc[1]);
        acc[2] = fmaf(w3, bf_lo(p3.y), acc[2]); acc[3] = fmaf(w3, bf_hi(p3.y), acc[3]);
        acc[4] = fmaf(w3, bf_lo(p3.z), acc[4]); acc[5] = fmaf(w3, bf_hi(p3.z), acc[5]);
        acc[6] = fmaf(w3, bf_lo(p3.w), acc[6]); acc[7] = fmaf(w3, bf_hi(p3.w), acc[7]);
    }

#pragma unroll
    for (int k = 0; k < 8; k++) {                   // sum the 4 groups
        acc[k] += __shfl_xor(acc[k], 16, 64);
        acc[k] += __shfl_xor(acc[k], 32, 64);
    }

    if (g == 0) {                                   // lanes 0..15 own dims 8s..8s+7
        const float4* hp4 = (const float4*)hprev;
        float4* ho4 = (float4*)hout;
        int idx = node * 32 + s * 2;
        float4 h0 = hp4[idx], h1 = hp4[idx + 1];
        float4 o0, o1;
        o0.x = h0.x + fmaxf(acc[0], 0.f); o0.y = h0.y + fmaxf(acc[1], 0.f);
        o0.z = h0.z + fmaxf(acc[2], 0.f); o0.w = h0.w + fmaxf(acc[3], 0.f);
        o1.x = h1.x + fmaxf(acc[4], 0.f); o1.y = h1.y + fmaxf(acc[5], 0.f);
        o1.z = h1.z + fmaxf(acc[6], 0.f); o1.w = h1.w + fmaxf(acc[7], 0.f);
        ho4[idx] = o0;
        ho4[idx + 1] = o1;
    }
}

// ---------------- launch ----------------------------------------------------

static inline size_t align_up(size_t x, size_t a) { return (x + a - 1) & ~(a - 1); }

extern "C" void kernel_launch(void* const* d_in, const int* in_sizes, int n_in,
                              void* d_out, int out_size, void* d_ws, size_t ws_size,
                              hipStream_t stream) {
    const float* x = (const float*)d_in[0];
    const int* ei = (const int*)d_in[1];
    const float* Wl[3] = {(const float*)d_in[2], (const float*)d_in[4], (const float*)d_in[6]};
    const float* bl[3] = {(const float*)d_in[3], (const float*)d_in[5], (const float*)d_in[7]};

    const int N = in_sizes[0] / D_DIM;                 // 50000 (requires N <= 4*LDSW, N < 65536)
    const int E = in_sizes[1] / 2;                     // 800000
    const int NW = N / 4;                              // 12500 packed words
    const int G = (N + SCAN_CHUNK - 1) / SCAN_CHUNK;   // 49 (must be <= 64)
    const int NWB = (NW + 255) / 256;                  // 49 word-blocks
    const int CHSZ = (E + CHUNKS - 1) / CHUNKS;        // 6250

    char* p = (char*)d_ws;
    int* col_cnt = (int*)p;            p += align_up((size_t)N * 4, 256);
    int* offs    = (int*)p;            p += align_up((size_t)(N + 1) * 4, 256);
    float* dis   = (float*)p;          p += align_up((size_t)N * 4, 256);
    int* bsum    = (int*)p;            p += align_up((size_t)64 * 4, 256);
    unsigned* partial_col = (unsigned*)p;  p += align_up((size_t)CHUNKS * LDSW * 4, 256);
    unsigned* partial_row = (unsigned*)p;  p += align_up((size_t)CHUNKS * LDSW * 4, 256);
    unsigned* gsum_col = (unsigned*)p; p += align_up((size_t)GROUPS * NW * 4, 256);
    unsigned* gsum_row = (unsigned*)p; p += align_up((size_t)GROUPS * NW * 4, 256);
    unsigned short* Wb = (unsigned short*)p;  p += align_up((size_t)3 * D_DIM * D_DIM * 2, 256);
    unsigned* epack = (unsigned*)p;    p += align_up((size_t)E * 4, 256);
    unsigned short* hWb = (unsigned short*)p;  p += align_up((size_t)N * D_DIM * 2, 256);
    (void)ws_size;

    int wcvt_blocks = (3 * D_DIM * D_DIM + 255) / 256;      // 192
    int hist_gx = (CHUNKS > wcvt_blocks) ? CHUNKS : wcvt_blocks;

    hist_kernel<<<dim3(hist_gx, 5), 256, 0, stream>>>(ei, partial_col, partial_row,
                                                      Wl[0], Wl[1], Wl[2], Wb, E, CHSZ);
    group_prefix_kernel<<<dim3(NWB, GROUPS, 2), 256, 0, stream>>>(partial_col, partial_row,
                                                                  gsum_col, gsum_row, NW);
    cnt_dis_kernel<<<NWB, 256, 0, stream>>>(gsum_col, gsum_row, col_cnt, dis, bsum, NW);
    scan_final_kernel<<<G, 256, 0, stream>>>(col_cnt, bsum, offs, N, G);
    scatter_kernel<<<dim3(CHUNKS, QUARTERS), 256, 0, stream>>>(ei, dis, offs, partial_col,
                                                               gsum_col, epack, E, CHSZ, NW);

    const float* hprev = x;
    float* h = (float*)d_out;
    int gemm_blocks = (N + 63) / 64;
    int agg_blocks = (N + 3) / 4;
    for (int l = 0; l < 3; l++) {
        linear_mfma_kernel<<<gemm_blocks, 256, 0, stream>>>(hprev, Wb + l * 16384, bl[l], hWb, N);
        agg_kernel<<<agg_blocks, 256, 0, stream>>>(offs, epack, (const uint4*)hWb, hprev, h, N);
        hprev = h;
    }
}

// Round 7
// 294.156 us; speedup vs baseline: 1.0349x; 1.0013x over previous
//
#include <hip/hip_runtime.h>
#include <hip/hip_bf16.h>

// GCN: 3 layers of  h = h + relu( segment_sum( norm * (h@W^T+b)[row], col ) )
// norm[e] = dis[row]*dis[col]*(row!=col), dis[v] = deg_row(v)>0 ? rsqrt(deg) : 0
// N=50000, D=128, E=800000. Harness compares in bf16 space (threshold 0.108):
// hW / GEMM inputs carried in bf16, accumulation fp32.
//
// R18: L0-GEMM fusion RETRY, now that hist LDS is 25KB (R13 failed at 50KB:
// every GEMM block inherited 50KB -> 3 blocks/CU). GEMM slice standalone caps
// at ~6 blocks/CU by VGPR (76) anyway; 25KB LDS cap = 6 blocks/CU = neutral.
// hist_kernel grid (782, 6): y=0..3 hist halves (ch<CHUNKS guard), y=4 wcvt
// (<192 guard), y=5 fused L0 GEMM (W0 read fp32 + inline cvt, stages in the
// aliased 25KB LDS). Layer loop skips linear for l=0. -1 serial dispatch+gap.
// R17 post-mortem: CHUNKS-halving (-150MB partials traffic) bought ~1us =>
// CSR kernels are per-block-LATENCY-bound, not traffic-bound. Serial chain
// length is the remaining structural fat.
// R17 (kept): CHUNKS=128; scatter quarter-split (12.5KB, 512 blocks); agg
// index-clamp form (R16 predication regressed +9us: clamp dupes free,
// exec-mask branches broke 4-chain issue).
// R15 (kept): hist node-range halving (25KB LDS, 6 blocks/CU cap).
// R12 (kept): agg 16 edges/round, 4 independent epack+gather chains; agg is
// gather-throughput-bound at its L2/L3 service floor.
// R11 (kept): quad-row dwordx4 gathers; shfl_xor(16|32) cross-group reduce.
// Kept lessons: no cooperative fusion (R7); no NT hints; packed-u8 counters
// valid (max degree ~45); global atomics at <64K-address density are
// contention-bound (R14: 74us @ 9% BW).

#define D_DIM 128
#define SCAN_CHUNK 1024
#define CHUNKS 128         // edge chunks
#define GROUPS 8
#define GS (CHUNKS / GROUPS)   // 16 chunks per group
#define LDSW 12512         // packed words: 4 bins/word -> 50048 bins >= N
#define HALVES 2
#define HWRD (LDSW / HALVES)   // 6256 words per half (25KB LDS) -- hist
#define HBINS (HWRD * 4)       // 25024 bins per half
#define QUARTERS 4
#define QWRD (LDSW / QUARTERS) // 3128 words per quarter (12.5KB LDS) -- scatter
#define QBINS (QWRD * 4)       // 12512 bins per quarter

typedef __attribute__((ext_vector_type(8))) short bf16x8;
typedef __attribute__((ext_vector_type(4))) float f32x4;

static __device__ __forceinline__ short f2bf(float f) {
    union { __hip_bfloat16 b; short s; } u;
    u.b = __float2bfloat16(f);
    return u.s;
}
static __device__ __forceinline__ float bf_lo(unsigned p) { return __uint_as_float(p << 16); }
static __device__ __forceinline__ float bf_hi(unsigned p) { return __uint_as_float(p & 0xffff0000u); }

// ---------------- CSR build (no global atomics, packed u8) ------------------

// grid (782, 6): y=0/1 col hist half 0/1, y=2/3 row hist half 0/1 (ch<CHUNKS),
// y=4 W->bf16 convert (<192 blocks), y=5 fused layer-0 linear (782 blocks).
// All paths share one 25KB LDS allocation (GEMM stages in an alias of it).
__global__ __launch_bounds__(256) void hist_kernel(const int* __restrict__ ei,
                                                   unsigned* __restrict__ partial_col,
                                                   unsigned* __restrict__ partial_row,
                                                   const float* __restrict__ W0,
                                                   const float* __restrict__ W1,
                                                   const float* __restrict__ W2,
                                                   unsigned short* __restrict__ Wb,
                                                   const float* __restrict__ x,
                                                   const float* __restrict__ b0,
                                                   unsigned short* __restrict__ hWb,
                                                   int nrows, int E, int CHSZ) {
    __shared__ unsigned hh[HWRD];
    int tid = threadIdx.x;
    if (blockIdx.y == 4) {                          // wcvt slice: 3*16384 elems
        int i = blockIdx.x * 256 + tid;
        if (i < 3 * D_DIM * D_DIM) {
            const float* W = (i < 16384) ? W0 : (i < 32768) ? W1 : W2;
            Wb[i] = (unsigned short)f2bf(W[i & 16383]);
        }
        return;
    }
    if (blockIdx.y == 5) {                          // fused layer-0 linear
        int wave = tid >> 6;
        int lane = tid & 63;
        int r0 = blockIdx.x * 64 + wave * 16;
        if (r0 >= nrows) return;
        int m = lane & 15, q = lane >> 4;
        int rload = min(r0 + m, nrows - 1);
        const float4* h4 = (const float4*)x;
        const float4* w4 = (const float4*)W0;

        f32x4 acc[8];
#pragma unroll
        for (int jt = 0; jt < 8; jt++) acc[jt] = (f32x4){0.f, 0.f, 0.f, 0.f};

#pragma unroll
        for (int k0 = 0; k0 < 128; k0 += 32) {
            int c0 = k0 + q * 8;
            float4 x0 = h4[rload * 32 + (c0 >> 2)];
            float4 x1 = h4[rload * 32 + (c0 >> 2) + 1];
            bf16x8 a;
            a[0] = f2bf(x0.x); a[1] = f2bf(x0.y); a[2] = f2bf(x0.z); a[3] = f2bf(x0.w);
            a[4] = f2bf(x1.x); a[5] = f2bf(x1.y); a[6] = f2bf(x1.z); a[7] = f2bf(x1.w);
#pragma unroll
            for (int jt = 0; jt < 8; jt++) {
                float4 w0v = w4[(jt * 16 + m) * 32 + (c0 >> 2)];
                float4 w1v = w4[(jt * 16 + m) * 32 + (c0 >> 2) + 1];
                bf16x8 b;
                b[0] = f2bf(w0v.x); b[1] = f2bf(w0v.y); b[2] = f2bf(w0v.z); b[3] = f2bf(w0v.w);
                b[4] = f2bf(w1v.x); b[5] = f2bf(w1v.y); b[6] = f2bf(w1v.z); b[7] = f2bf(w1v.w);
                acc[jt] = __builtin_amdgcn_mfma_f32_16x16x32_bf16(a, b, acc[jt], 0, 0, 0);
            }
        }
        unsigned short* stg = (unsigned short*)hh + wave * 16 * 136;  // LDS alias
#pragma unroll
        for (int jt = 0; jt < 8; jt++) {
            float bv = b0[jt * 16 + m];
#pragma unroll
            for (int reg = 0; reg < 4; reg++)
                stg[(q * 4 + reg) * 136 + jt * 16 + m] =
                    (unsigned short)f2bf(acc[jt][reg] + bv);
        }
#pragma unroll
        for (int t = 0; t < 4; t++) {
            int rl = t * 4 + (lane >> 4);
            int gr = r0 + rl;
            if (gr < nrows) {
                uint4 v = *(const uint4*)&stg[rl * 136 + (lane & 15) * 8];
                *(uint4*)&hWb[(size_t)gr * D_DIM + (lane & 15) * 8] = v;
            }
        }
        return;
    }
    int ch = blockIdx.x;
    if (ch >= CHUNKS) return;                       // grid.x widened for y>=4
    int docol = (blockIdx.y < 2);
    int half = blockIdx.y & 1;
    int bin0 = half * HBINS;
    for (int i = tid; i < HWRD; i += 256) hh[i] = 0u;
    __syncthreads();
    int e0 = ch * CHSZ, e1 = min(e0 + CHSZ, E);
    for (int e = e0 + tid; e < e1; e += 256) {
        int row = ei[e];
        int col = ei[E + e];
        if (row == col) continue;                  // remove_self_loops
        int rb = (docol ? col : row) - bin0;
        if ((unsigned)rb < (unsigned)HBINS)
            atomicAdd(&hh[rb >> 2], 1u << ((rb & 3) * 8));
    }
    __syncthreads();
    unsigned* dst = (docol ? partial_col : partial_row) + (size_t)ch * LDSW + half * HWRD;
    for (int i = tid; i < HWRD; i += 256) dst[i] = hh[i];
}

// grid (ceil(NW/256), GROUPS, 2). z=0: in-place exclusive prefix of col counts
// over the group's GS chunks + group sum. z=1: row group sums only.
__global__ __launch_bounds__(256) void group_prefix_kernel(
    unsigned* __restrict__ partial_col, const unsigned* __restrict__ partial_row,
    unsigned* __restrict__ gsum_col, unsigned* __restrict__ gsum_row, int NW) {
    int w = blockIdx.x * 256 + threadIdx.x;
    if (w >= NW) return;
    int g = blockIdx.y;
    size_t base = (size_t)(g * GS) * LDSW + w;
    if (blockIdx.z == 0) {
        unsigned run = 0;
#pragma unroll 4
        for (int c = 0; c < GS; c++) {
            unsigned v = partial_col[base + (size_t)c * LDSW];
            partial_col[base + (size_t)c * LDSW] = run;
            run += v;
        }
        gsum_col[g * NW + w] = run;
    } else {
        unsigned run = 0;
#pragma unroll 4
        for (int c = 0; c < GS; c++) run += partial_row[base + (size_t)c * LDSW];
        gsum_row[g * NW + w] = run;
    }
}

// per packed word: sum the GROUPS group words -> col_cnt int4, dis float4,
// per-SCAN_CHUNK block sums, AND in-place exclusive prefix of gsum_col over
// groups (values already in registers -- replaces the gpref launch).
__global__ __launch_bounds__(256) void cnt_dis_kernel(
    unsigned* __restrict__ gsum_col, const unsigned* __restrict__ gsum_row,
    int* __restrict__ col_cnt, float* __restrict__ dis, int* __restrict__ bsum, int NW) {
    __shared__ int wsum[4];
    int w = blockIdx.x * 256 + threadIdx.x;
    int s = 0;
    if (w < NW) {
        unsigned wcv[GROUPS];
        unsigned clo = 0, chi = 0, rlo = 0, rhi = 0;
#pragma unroll
        for (int g = 0; g < GROUPS; g++) {
            unsigned wc = gsum_col[g * NW + w];
            unsigned wr = gsum_row[g * NW + w];
            wcv[g] = wc;
            clo += wc & 0x00FF00FFu; chi += (wc >> 8) & 0x00FF00FFu;
            rlo += wr & 0x00FF00FFu; rhi += (wr >> 8) & 0x00FF00FFu;
        }
        unsigned run = 0;
#pragma unroll
        for (int g = 0; g < GROUPS; g++) {         // exclusive prefix (packed u8)
            gsum_col[g * NW + w] = run;
            run += wcv[g];
        }
        int c0 = clo & 0xFFFF, c1 = chi & 0xFFFF, c2 = clo >> 16, c3 = chi >> 16;
        int r0 = rlo & 0xFFFF, r1 = rhi & 0xFFFF, r2 = rlo >> 16, r3 = rhi >> 16;
        ((int4*)col_cnt)[w] = make_int4(c0, c1, c2, c3);
        float4 dv;
        dv.x = (r0 > 0) ? rsqrtf((float)r0) : 0.0f;
        dv.y = (r1 > 0) ? rsqrtf((float)r1) : 0.0f;
        dv.z = (r2 > 0) ? rsqrtf((float)r2) : 0.0f;
        dv.w = (r3 > 0) ? rsqrtf((float)r3) : 0.0f;
        ((float4*)dis)[w] = dv;
        s = c0 + c1 + c2 + c3;
    }
#pragma unroll
    for (int d = 32; d > 0; d >>= 1) s += __shfl_down(s, d, 64);
    int lane = threadIdx.x & 63, wv = threadIdx.x >> 6;
    if (lane == 0) wsum[wv] = s;
    __syncthreads();
    if (threadIdx.x == 0) bsum[blockIdx.x] = wsum[0] + wsum[1] + wsum[2] + wsum[3];
}

// grid (G): local exclusive scan + inline cross-block base (wave 0 scans the
// G<=64 bsums redundantly per block).
__global__ __launch_bounds__(256) void scan_final_kernel(const int* __restrict__ cnt,
                                                         const int* __restrict__ bsum,
                                                         int* __restrict__ offs,
                                                         int n, int G) {
    __shared__ int wsum[4];
    __shared__ int sblock;
    int base = blockIdx.x * SCAN_CHUNK;
    int tid = threadIdx.x;
    const int PT = SCAN_CHUNK / 256;
    int v[PT];
    int s = 0;
#pragma unroll
    for (int i = 0; i < PT; i++) {
        int g = base + tid * PT + i;
        v[i] = (g < n) ? cnt[g] : 0;
        s += v[i];
    }
    int local_sum = s;
    int lane = tid & 63, w = tid >> 6;
#pragma unroll
    for (int d = 1; d < 64; d <<= 1) {
        int t = __shfl_up(s, d, 64);
        if (lane >= d) s += t;
    }
    if (lane == 63) wsum[w] = s;
    if (tid < 64) {
        int bv = (tid < G) ? bsum[tid] : 0;
        int bs = bv;
#pragma unroll
        for (int d = 1; d < 64; d <<= 1) {
            int t = __shfl_up(bs, d, 64);
            if (tid >= d) bs += t;
        }
        if (tid == blockIdx.x) sblock = bs - bv;            // exclusive base
        if (tid == 63 && blockIdx.x == G - 1) offs[n] = bs; // grand total
    }
    __syncthreads();
    int wbase = 0;
    for (int i = 0; i < w; i++) wbase += wsum[i];
    int run = sblock + wbase + (s - local_sum);
#pragma unroll
    for (int i = 0; i < PT; i++) {
        int g = base + tid * PT + i;
        if (g < n) offs[g] = run;
        run += v[i];
    }
}

// grid (CHUNKS, QUARTERS): LDS cursors (12.5KB, quarter node range) seeded
// with chunk_prefix + group-exclusive base. slot = offs[col] + byte(old).
// epack entry: row:u16 | norm:bf16. Edges outside the quarter are skipped.
__global__ __launch_bounds__(256) void scatter_kernel(const int* __restrict__ ei,
                                                      const float* __restrict__ dis,
                                                      const int* __restrict__ offs,
                                                      const unsigned* __restrict__ chpref,
                                                      const unsigned* __restrict__ gpref,
                                                      unsigned* __restrict__ epack,
                                                      int E, int CHSZ, int NW) {
    __shared__ unsigned cur[QWRD];
    int tid = threadIdx.x;
    int ch = blockIdx.x;
    int q = blockIdx.y;
    int wbase = q * QWRD;                          // word offset of this quarter
    int bin0 = q * QBINS;
    const unsigned* pf = chpref + (size_t)ch * LDSW + wbase;
    const unsigned* gb = gpref + (size_t)(ch / GS) * NW;
    for (int i = tid; i < QWRD; i += 256) {
        unsigned seed = pf[i];
        int w = wbase + i;
        if (w < NW) seed += gb[w];
        cur[i] = seed;
    }
    __syncthreads();
    int e0 = ch * CHSZ, e1 = min(e0 + CHSZ, E);
    for (int e = e0 + tid; e < e1; e += 256) {
        int row = ei[e];
        int col = ei[E + e];
        if (row == col) continue;
        int rb = col - bin0;
        if ((unsigned)rb >= (unsigned)QBINS) continue;   // other quarter
        float wgt = dis[row] * dis[col];
        int wd = rb >> 2, sh = (rb & 3) * 8;
        unsigned old = atomicAdd(&cur[wd], 1u << sh);
        int slot = offs[col] + (int)((old >> sh) & 0xFFu);
        epack[slot] = (unsigned)row | ((unsigned)(unsigned short)f2bf(wgt) << 16);
    }
}

// ---------------- per-layer kernels ----------------------------------------

// hWb[r][j] = bf16( b[j] + sum_k h[r][k] * W[j][k] )  via 16x16x32 bf16 MFMA.
// Wave: 16 rows x 128 cols. C/D layout: col=lane&15, row=(lane>>4)*4+reg.
// Epilogue stages the bf16 tile in LDS then stores 4x contiguous 1KB/wave.
__global__ __launch_bounds__(256) void linear_mfma_kernel(
    const float* __restrict__ A, const unsigned short* __restrict__ Wb,
    const float* __restrict__ bias, unsigned short* __restrict__ hWb, int nrows) {
    __shared__ unsigned short stage[4][16 * 136];
    int wave = threadIdx.x >> 6;
    int lane = threadIdx.x & 63;
    int r0 = blockIdx.x * 64 + wave * 16;
    int m = lane & 15, q = lane >> 4;
    int rload = min(r0 + m, nrows - 1);
    const float4* h4 = (const float4*)A;

    f32x4 acc[8];
#pragma unroll
    for (int jt = 0; jt < 8; jt++) acc[jt] = (f32x4){0.f, 0.f, 0.f, 0.f};

#pragma unroll
    for (int k0 = 0; k0 < 128; k0 += 32) {
        int c0 = k0 + q * 8;
        float4 x0 = h4[rload * 32 + (c0 >> 2)];
        float4 x1 = h4[rload * 32 + (c0 >> 2) + 1];
        bf16x8 a;
        a[0] = f2bf(x0.x); a[1] = f2bf(x0.y); a[2] = f2bf(x0.z); a[3] = f2bf(x0.w);
        a[4] = f2bf(x1.x); a[5] = f2bf(x1.y); a[6] = f2bf(x1.z); a[7] = f2bf(x1.w);
#pragma unroll
        for (int jt = 0; jt < 8; jt++) {
            bf16x8 b = *(const bf16x8*)(Wb + (jt * 16 + m) * D_DIM + c0);
            acc[jt] = __builtin_amdgcn_mfma_f32_16x16x32_bf16(a, b, acc[jt], 0, 0, 0);
        }
    }

#pragma unroll
    for (int jt = 0; jt < 8; jt++) {
        float bv = bias[jt * 16 + m];
#pragma unroll
        for (int reg = 0; reg < 4; reg++)
            stage[wave][(q * 4 + reg) * 136 + jt * 16 + m] =
                (unsigned short)f2bf(acc[jt][reg] + bv);
    }
#pragma unroll
    for (int t = 0; t < 4; t++) {
        int rl = t * 4 + (lane >> 4);
        int gr = r0 + rl;
        if (gr < nrows) {
            uint4 v = *(const uint4*)&stage[wave][rl * 136 + (lane & 15) * 8];
            *(uint4*)&hWb[(size_t)gr * D_DIM + (lane & 15) * 8] = v;
        }
    }
}

// one wave per destination node; quad-row gathers: lane (g=lane>>4, s=lane&15)
// loads 16B (dims 8s..8s+7) of an edge row per dwordx4. 16 edges/round --
// group g takes slots i+g, i+4+g, i+8+g, i+12+g; 4 epack loads + 4 gathers
// issued as independent chains per round; ragged ends via index clamp +
// weight zeroing (R16: predication regressed; clamp dupes are free). fp32
// acc; shfl_xor(16|32) cross-group reduce; group-0 float4 epilogue
// h_out = h_prev + relu(acc).
__global__ __launch_bounds__(256) void agg_kernel(const int* __restrict__ offs,
                                                  const unsigned* __restrict__ epack,
                                                  const uint4* __restrict__ hW4,
                                                  const float* __restrict__ hprev,
                                                  float* __restrict__ hout, int n_nodes) {
    int node = (int)((blockIdx.x * blockDim.x + threadIdx.x) >> 6);
    int lane = threadIdx.x & 63;
    if (node >= n_nodes) return;
    int g = lane >> 4, s = lane & 15;

    int beg = offs[node];
    int end = offs[node + 1];

    float acc[8];
#pragma unroll
    for (int k = 0; k < 8; k++) acc[k] = 0.f;

    for (int i = beg; i < end; i += 16) {
        int last = end - 1;
        int i0 = i + g, i1 = i0 + 4, i2 = i0 + 8, i3 = i0 + 12;
        unsigned e0 = epack[min(i0, last)];
        unsigned e1 = epack[min(i1, last)];
        unsigned e2 = epack[min(i2, last)];
        unsigned e3 = epack[min(i3, last)];
        uint4 p0 = hW4[(e0 & 0xffffu) * 16 + s];
        uint4 p1 = hW4[(e1 & 0xffffu) * 16 + s];
        uint4 p2 = hW4[(e2 & 0xffffu) * 16 + s];
        uint4 p3 = hW4[(e3 & 0xffffu) * 16 + s];
        float w0 = (i0 < end) ? bf_hi(e0) : 0.f;
        float w1 = (i1 < end) ? bf_hi(e1) : 0.f;
        float w2 = (i2 < end) ? bf_hi(e2) : 0.f;
        float w3 = (i3 < end) ? bf_hi(e3) : 0.f;
        acc[0] = fmaf(w0, bf_lo(p0.x), acc[0]); acc[1] = fmaf(w0, bf_hi(p0.x), acc[1]);
        acc[2] = fmaf(w0, bf_lo(p0.y), acc[2]); acc[3] = fmaf(w0, bf_hi(p0.y), acc[3]);
        acc[4] = fmaf(w0, bf_lo(p0.z), acc[4]); acc[5] = fmaf(w0, bf_hi(p0.z), acc[5]);
        acc[6] = fmaf(w0, bf_lo(p0.w), acc[6]); acc[7] = fmaf(w0, bf_hi(p0.w), acc[7]);
        acc[0] = fmaf(w1, bf_lo(p1.x), acc[0]); acc[1] = fmaf(w1, bf_hi(p1.x), acc[1]);
        acc[2] = fmaf(w1, bf_lo(p1.y), acc[2]); acc[3] = fmaf(w1, bf_hi(p1.y), acc[3]);
        acc[4] = fmaf(w1, bf_lo(p1.z), acc[4]); acc[5] = fmaf(w1, bf_hi(p1.z), acc[5]);
        acc[6] = fmaf(w1, bf_lo(p1.w), acc[6]); acc[7] = fmaf(w1, bf_hi(p1.w), acc[7]);
        acc[0] = fmaf(w2, bf_lo(p2.x), acc[0]); acc[1] = fmaf(w2, bf_hi(p2.x), acc[1]);
        acc[2] = fmaf(w2, bf_lo(p2.y), acc[2]); acc[3] = fmaf(w2, bf_hi(p2.y), acc[3]);
        acc[4] = fmaf(w2, bf_lo(p2.z), acc[4]); acc[5] = fmaf(w2, bf_hi(p2.z), acc[5]);
        acc[6] = fmaf(w2, bf_lo(p2.w), acc[6]); acc[7] = fmaf(w2, bf_hi(p2.w), acc[7]);
        acc[0] = fmaf(w3, bf_lo(p3.x), acc[0]); acc[1] = fmaf(w3, bf_hi(p3.x), acc[1]);
        acc[2] = fmaf(w3, bf_lo(p3.y), acc[2]); acc[3] = fmaf(w3, bf_hi(p3.y), acc[3]);
        acc[4] = fmaf(w3, bf_lo(p3.z), acc[4]); acc[5] = fmaf(w3, bf_hi(p3.z), acc[5]);
        acc[6] = fmaf(w3, bf_lo(p3.w), acc[6]); acc[7] = fmaf(w3, bf_hi(p3.w), acc[7]);
    }

#pragma unroll
    for (int k = 0; k < 8; k++) {                   // sum the 4 groups
        acc[k] += __shfl_xor(acc[k], 16, 64);
        acc[k] += __shfl_xor(acc[k], 32, 64);
    }

    if (g == 0) {                                   // lanes 0..15 own dims 8s..8s+7
        const float4* hp4 = (const float4*)hprev;
        float4* ho4 = (float4*)hout;
        int idx = node * 32 + s * 2;
        float4 h0 = hp4[idx], h1 = hp4[idx + 1];
        float4 o0, o1;
        o0.x = h0.x + fmaxf(acc[0], 0.f); o0.y = h0.y + fmaxf(acc[1], 0.f);
        o0.z = h0.z + fmaxf(acc[2], 0.f); o0.w = h0.w + fmaxf(acc[3], 0.f);
        o1.x = h1.x + fmaxf(acc[4], 0.f); o1.y = h1.y + fmaxf(acc[5], 0.f);
        o1.z = h1.z + fmaxf(acc[6], 0.f); o1.w = h1.w + fmaxf(acc[7], 0.f);
        ho4[idx] = o0;
        ho4[idx + 1] = o1;
    }
}

// ---------------- launch ----------------------------------------------------

static inline size_t align_up(size_t x, size_t a) { return (x + a - 1) & ~(a - 1); }

extern "C" void kernel_launch(void* const* d_in, const int* in_sizes, int n_in,
                              void* d_out, int out_size, void* d_ws, size_t ws_size,
                              hipStream_t stream) {
    const float* x = (const float*)d_in[0];
    const int* ei = (const int*)d_in[1];
    const float* Wl[3] = {(const float*)d_in[2], (const float*)d_in[4], (const float*)d_in[6]};
    const float* bl[3] = {(const float*)d_in[3], (const float*)d_in[5], (const float*)d_in[7]};

    const int N = in_sizes[0] / D_DIM;                 // 50000 (requires N <= 4*LDSW, N < 65536)
    const int E = in_sizes[1] / 2;                     // 800000
    const int NW = N / 4;                              // 12500 packed words
    const int G = (N + SCAN_CHUNK - 1) / SCAN_CHUNK;   // 49 (must be <= 64)
    const int NWB = (NW + 255) / 256;                  // 49 word-blocks
    const int CHSZ = (E + CHUNKS - 1) / CHUNKS;        // 6250

    char* p = (char*)d_ws;
    int* col_cnt = (int*)p;            p += align_up((size_t)N * 4, 256);
    int* offs    = (int*)p;            p += align_up((size_t)(N + 1) * 4, 256);
    float* dis   = (float*)p;          p += align_up((size_t)N * 4, 256);
    int* bsum    = (int*)p;            p += align_up((size_t)64 * 4, 256);
    unsigned* partial_col = (unsigned*)p;  p += align_up((size_t)CHUNKS * LDSW * 4, 256);
    unsigned* partial_row = (unsigned*)p;  p += align_up((size_t)CHUNKS * LDSW * 4, 256);
    unsigned* gsum_col = (unsigned*)p; p += align_up((size_t)GROUPS * NW * 4, 256);
    unsigned* gsum_row = (unsigned*)p; p += align_up((size_t)GROUPS * NW * 4, 256);
    unsigned short* Wb = (unsigned short*)p;  p += align_up((size_t)3 * D_DIM * D_DIM * 2, 256);
    unsigned* epack = (unsigned*)p;    p += align_up((size_t)E * 4, 256);
    unsigned short* hWb = (unsigned short*)p;  p += align_up((size_t)N * D_DIM * 2, 256);
    (void)ws_size;

    int gemm_blocks = (N + 63) / 64;                   // 782
    int hist_gx = gemm_blocks;                         // covers CHUNKS and wcvt too

    hist_kernel<<<dim3(hist_gx, 6), 256, 0, stream>>>(ei, partial_col, partial_row,
                                                      Wl[0], Wl[1], Wl[2], Wb,
                                                      x, bl[0], hWb, N, E, CHSZ);
    group_prefix_kernel<<<dim3(NWB, GROUPS, 2), 256, 0, stream>>>(partial_col, partial_row,
                                                                  gsum_col, gsum_row, NW);
    cnt_dis_kernel<<<NWB, 256, 0, stream>>>(gsum_col, gsum_row, col_cnt, dis, bsum, NW);
    scan_final_kernel<<<G, 256, 0, stream>>>(col_cnt, bsum, offs, N, G);
    scatter_kernel<<<dim3(CHUNKS, QUARTERS), 256, 0, stream>>>(ei, dis, offs, partial_col,
                                                               gsum_col, epack, E, CHSZ, NW);

    const float* hprev = x;
    float* h = (float*)d_out;
    int agg_blocks = (N + 3) / 4;
    for (int l = 0; l < 3; l++) {
        if (l > 0)
            linear_mfma_kernel<<<gemm_blocks, 256, 0, stream>>>(hprev, Wb + l * 16384,
                                                                bl[l], hWb, N);
        agg_kernel<<<agg_blocks, 256, 0, stream>>>(offs, epack, (const uint4*)hWb, hprev, h, N);
        hprev = h;
    }
}